// Round 13
// baseline (44.834 us; speedup 1.0000x reference)
//
#include <hip/hip_runtime.h>
#include <math.h>

#define NEG_SLOPE 0.2f
#define LOG2E 1.44269504088896f

#if __has_builtin(__builtin_amdgcn_exp2f)
#define EXP2F __builtin_amdgcn_exp2f
#else
#define EXP2F exp2f
#endif

typedef _Float16 f16x8 __attribute__((ext_vector_type(8)));
typedef __fp16 h16x2 __attribute__((ext_vector_type(2)));   // cvt_pkrtz native type
typedef float f32x4 __attribute__((ext_vector_type(4)));
typedef float f32x2 __attribute__((ext_vector_type(2)));

union PK8 { uint4 u4; _Float16 h[8]; f16x8 v; h16x2 p[4]; };
union PK1 { unsigned short u; _Float16 h; };

#define XN_CHUNKS (32 * 512 * 256 / 8)   // 524288 x-chunks of 8
#define WN_CHUNKS (256 * 256 / 8)        // 8192 W-chunks of 8

// ---------------------------------------------------------------------------
// Kernel 0: one-shot f32 -> f16 convert of x and W (each element exactly once).
// ~25 MB traffic, HBM-bound, ~4 us.
// ---------------------------------------------------------------------------
__global__ __launch_bounds__(256) void cvt_f16(const float* __restrict__ x,
                                               const float* __restrict__ W,
                                               unsigned short* __restrict__ xf,
                                               unsigned short* __restrict__ wf) {
    int idx = blockIdx.x * 256 + threadIdx.x;
    const float* src;
    unsigned short* dst;
    if (idx < XN_CHUNKS) {
        src = x + (size_t)idx * 8;
        dst = xf + (size_t)idx * 8;
    } else {
        int j = idx - XN_CHUNKS;
        if (j >= WN_CHUNKS) return;
        src = W + (size_t)j * 8;
        dst = wf + (size_t)j * 8;
    }
    float4 v0 = *(const float4*)(src);
    float4 v1 = *(const float4*)(src + 4);
    PK8 p;
    p.p[0] = __builtin_amdgcn_cvt_pkrtz(v0.x, v0.y);
    p.p[1] = __builtin_amdgcn_cvt_pkrtz(v0.z, v0.w);
    p.p[2] = __builtin_amdgcn_cvt_pkrtz(v1.x, v1.y);
    p.p[3] = __builtin_amdgcn_cvt_pkrtz(v1.z, v1.w);
    *(uint4*)dst = p.u4;
}

// ---------------------------------------------------------------------------
// Fused GAT kernel. Grid 256 = (b,h) with bid = h*32 + b (bid%8 = b%8 =>
// all 8 heads of a batch share an XCD => x[b] L2-hot). 1024 thr = 16 waves
// (4/SIMD). Phase 1: BARRIER-FREE slice-GEMM — af (W rows, L1-resident) and
// bf (x rows) loaded straight from f16 globals, no staging LDS. Wave w owns
// j = w*32..w*32+31 (jt in {0,1}). Phase 2: scores from f32 accumulators
// (in-register; PV wave's i-rows == its score j-cols, so ciK stays in-lane);
// wxt[32][512] f16 -> LDS (swizzled). ONE barrier. Phase 3: proven PV
// (packed P-gen + EXP2F + 4 MFMA/kk) + ELU epilogue.
// ---------------------------------------------------------------------------
__global__ __launch_bounds__(1024) void gat_fused(const unsigned short* __restrict__ xf,
                                                  const unsigned short* __restrict__ wf,
                                                  const float* __restrict__ attn,
                                                  float* __restrict__ out) {
    __shared__ __align__(16) unsigned short wxt[32 * 512];  // [d][j] f16, row 1KB, swz (d&7)<<4
    __shared__ float stf[512];    // s_tgt * LOG2E
    __shared__ float red_s[16];

    const int bid = blockIdx.x;
    const int b = bid & 31, h = bid >> 5;
    const int tid = threadIdx.x;
    const int w = tid >> 6, l = tid & 63;
    const int q = l >> 4, ln = l & 15;

    // ---- Phase 1: barrier-free GEMM. gacc[dt][jt]: C row=d-local, col=j ----
    const unsigned short* xb = xf + (size_t)b * 512 * 256;
    const unsigned short* wh = wf + h * 32 * 256;

    f32x4 gacc[2][2];
    #pragma unroll
    for (int dt = 0; dt < 2; ++dt)
        #pragma unroll
        for (int jt = 0; jt < 2; ++jt) gacc[dt][jt] = (f32x4){0.f, 0.f, 0.f, 0.f};

    #pragma unroll 2
    for (int ks = 0; ks < 8; ++ks) {
        const int k0 = ks * 32 + q * 8;
        f16x8 af[2], bf[2];
        #pragma unroll
        for (int dt = 0; dt < 2; ++dt) {
            PK8 pk;
            pk.u4 = *(const uint4*)(wh + (size_t)(dt * 16 + ln) * 256 + k0);
            af[dt] = pk.v;
        }
        #pragma unroll
        for (int jt = 0; jt < 2; ++jt) {
            int j = w * 32 + jt * 16 + ln;
            PK8 pk;
            pk.u4 = *(const uint4*)(xb + (size_t)j * 256 + k0);
            bf[jt] = pk.v;
        }
        #pragma unroll
        for (int dt = 0; dt < 2; ++dt)
            #pragma unroll
            for (int jt = 0; jt < 2; ++jt)
                gacc[dt][jt] = __builtin_amdgcn_mfma_f32_16x16x32_f16(af[dt], bf[jt],
                                                                      gacc[dt][jt], 0, 0, 0);
    }

    // ---- Phase 2: scores in-register + wxt -> LDS ----
    float av_s[2][4], av_t[2][4];
    #pragma unroll
    for (int dt = 0; dt < 2; ++dt)
        #pragma unroll
        for (int r = 0; r < 4; ++r) {
            int d = dt * 16 + q * 4 + r;
            av_s[dt][r] = attn[h * 64 + d];
            av_t[dt][r] = attn[h * 64 + 32 + d];
        }

    float ciK[2];
    #pragma unroll
    for (int jt = 0; jt < 2; ++jt) {
        float ps = 0.f, pt = 0.f;
        #pragma unroll
        for (int dt = 0; dt < 2; ++dt)
            #pragma unroll
            for (int r = 0; r < 4; ++r) {
                float v = gacc[dt][jt][r];
                ps += v * av_s[dt][r];
                pt += v * av_t[dt][r];
            }
        ps += __shfl_xor(ps, 16); ps += __shfl_xor(ps, 32);
        pt += __shfl_xor(pt, 16); pt += __shfl_xor(pt, 32);
        int j = w * 32 + jt * 16 + ln;
        ciK[jt] = ps * LOG2E;                     // this wave's PV rows == these j
        if (q == 0) stf[j] = pt * LOG2E;
        #pragma unroll
        for (int dt = 0; dt < 2; ++dt)
            #pragma unroll
            for (int r = 0; r < 4; ++r) {
                int d = dt * 16 + q * 4 + r;
                PK1 hv; hv.h = (_Float16)gacc[dt][jt][r];
                *(unsigned short*)((char*)wxt + (((d << 10) + j * 2) ^ ((d & 7) << 4))) = hv.u;
            }
    }
    __syncthreads();

    // ---- block max of stf ----
    {
        float m = stf[(w * 64 + l) & 511];
        #pragma unroll
        for (int off = 32; off > 0; off >>= 1)
            m = fmaxf(m, __shfl_xor(m, off));
        if (l == 0) red_s[w] = m;
    }
    __syncthreads();
    float maxtK = red_s[0];
    #pragma unroll
    for (int ww = 1; ww < 16; ++ww) maxtK = fmaxf(maxtK, red_s[ww]);

    float miK[2];
    #pragma unroll
    for (int g = 0; g < 2; ++g) {
        float cm = ciK[g] + maxtK;
        miK[g] = fmaxf(cm, NEG_SLOPE * cm);
    }

    // ---- Phase 3: PV. Wave owns rows i = w*32 + g*16 + ln ----
    f32x4 acc[2][2];
    #pragma unroll
    for (int g = 0; g < 2; ++g) {
        acc[g][0] = (f32x4){0.f, 0.f, 0.f, 0.f};
        acc[g][1] = (f32x4){0.f, 0.f, 0.f, 0.f};
    }
    f32x2 pdv[2] = {(f32x2){0.f, 0.f}, (f32x2){0.f, 0.f}};

    for (int kk = 0; kk < 16; ++kk) {
        f16x8 bf[2];
        #pragma unroll
        for (int dt = 0; dt < 2; ++dt) {
            int d = dt * 16 + ln;
            int bb = d * 1024 + kk * 64 + q * 16;
            PK8 pk;
            pk.u4 = *(const uint4*)((const char*)wxt + (bb ^ ((d & 7) << 4)));
            bf[dt] = pk.v;
        }
        const int j0 = kk * 32 + q * 8;
        f32x2 stp[4];
        {
            float4 s0 = *(const float4*)(stf + j0);
            float4 s1 = *(const float4*)(stf + j0 + 4);
            stp[0] = (f32x2){s0.x, s0.y};
            stp[1] = (f32x2){s0.z, s0.w};
            stp[2] = (f32x2){s1.x, s1.y};
            stp[3] = (f32x2){s1.z, s1.w};
        }

        #pragma unroll
        for (int g = 0; g < 2; ++g) {
            const f32x2 ci2 = (f32x2){ciK[g], ciK[g]};
            const f32x2 mi2 = (f32x2){miK[g], miK[g]};
            PK8 pa;
            #pragma unroll
            for (int pr = 0; pr < 4; ++pr) {
                f32x2 e  = ci2 + stp[pr];                           // v_pk_add
                f32x2 a1 = e - mi2;                                 // v_pk_add(-)
                f32x2 a2 = (f32x2){NEG_SLOPE, NEG_SLOPE} * e - mi2; // v_pk_fma
                float m0 = fmaxf(a1.x, a2.x);
                float m1 = fmaxf(a1.y, a2.y);
                float p0 = EXP2F(m0);
                float p1 = EXP2F(m1);
                pdv[g] += (f32x2){p0, p1};                          // v_pk_add
                pa.p[pr] = __builtin_amdgcn_cvt_pkrtz(p0, p1);      // 1 cvt
            }
            acc[g][0] = __builtin_amdgcn_mfma_f32_16x16x32_f16(pa.v, bf[0], acc[g][0], 0, 0, 0);
            acc[g][1] = __builtin_amdgcn_mfma_f32_16x16x32_f16(pa.v, bf[1], acc[g][1], 0, 0, 0);
        }
    }

    // ---- epilogue: denominators, ELU, store ----
    float inv[2];
    #pragma unroll
    for (int g = 0; g < 2; ++g) {
        float s = pdv[g].x + pdv[g].y;
        s += __shfl_xor(s, 16);
        s += __shfl_xor(s, 32);
        inv[g] = 1.f / s;
    }
    #pragma unroll
    for (int g = 0; g < 2; ++g)
        #pragma unroll
        for (int dt = 0; dt < 2; ++dt)
            #pragma unroll
            for (int r = 0; r < 4; ++r) {
                int row = q * 4 + r;
                float dn = __shfl(inv[g], row);    // lane 'row' holds that row's denom
                float o = acc[g][dt][r] * dn;
                o = o > 0.f ? o : (__expf(o) - 1.f);
                size_t i = (size_t)(b * 512 + w * 32 + g * 16 + row);
                out[i * 256 + h * 32 + dt * 16 + ln] = o;
            }
}

// ---------------------------------------------------------------------------
extern "C" void kernel_launch(void* const* d_in, const int* in_sizes, int n_in,
                              void* d_out, int out_size, void* d_ws, size_t ws_size,
                              hipStream_t stream) {
    const float* x    = (const float*)d_in[0];   // (32,512,256)
    const float* W    = (const float*)d_in[1];   // (256,256)
    const float* attn = (const float*)d_in[2];   // (1,8,64)
    float* out = (float*)d_out;                  // (32,512,256)

    unsigned short* xf = (unsigned short*)d_ws;               // f16 x, 8.39 MB
    unsigned short* wf = xf + (size_t)32 * 512 * 256;         // f16 W, 131 KB

    cvt_f16<<<(XN_CHUNKS + WN_CHUNKS + 255) / 256, 256, 0, stream>>>(x, W, xf, wf);
    gat_fused<<<256, 1024, 0, stream>>>(xf, wf, attn, out);
}

// Round 14
// 41.897 us; speedup vs baseline: 1.0701x; 1.0701x over previous
//
#include <hip/hip_runtime.h>
#include <math.h>

#define NEG_SLOPE 0.2f
#define LOG2E 1.44269504088896f

#if __has_builtin(__builtin_amdgcn_exp2f)
#define EXP2F __builtin_amdgcn_exp2f
#else
#define EXP2F exp2f
#endif

typedef _Float16 f16x8 __attribute__((ext_vector_type(8)));
typedef __fp16 h16x2 __attribute__((ext_vector_type(2)));   // cvt_pkrtz native type
typedef float f32x4 __attribute__((ext_vector_type(4)));

union PK8 { uint4 u4; _Float16 h[8]; f16x8 v; h16x2 p[4]; };
union PK1 { unsigned short u; _Float16 h; };

#define XN_CHUNKS (32 * 512 * 256 / 8)   // 524288 x-chunks of 8
#define WN_CHUNKS (256 * 256 / 8)        // 8192 W-chunks of 8

// ---------------------------------------------------------------------------
// Kernel 0: one-shot f32 -> f16 convert of x and W (each element exactly once).
// ---------------------------------------------------------------------------
__global__ __launch_bounds__(256) void cvt_f16(const float* __restrict__ x,
                                               const float* __restrict__ W,
                                               unsigned short* __restrict__ xf,
                                               unsigned short* __restrict__ wf) {
    int idx = blockIdx.x * 256 + threadIdx.x;
    const float* src;
    unsigned short* dst;
    if (idx < XN_CHUNKS) {
        src = x + (size_t)idx * 8;
        dst = xf + (size_t)idx * 8;
    } else {
        int j = idx - XN_CHUNKS;
        if (j >= WN_CHUNKS) return;
        src = W + (size_t)j * 8;
        dst = wf + (size_t)j * 8;
    }
    float4 v0 = *(const float4*)(src);
    float4 v1 = *(const float4*)(src + 4);
    PK8 p;
    p.p[0] = __builtin_amdgcn_cvt_pkrtz(v0.x, v0.y);
    p.p[1] = __builtin_amdgcn_cvt_pkrtz(v0.z, v0.w);
    p.p[2] = __builtin_amdgcn_cvt_pkrtz(v1.x, v1.y);
    p.p[3] = __builtin_amdgcn_cvt_pkrtz(v1.z, v1.w);
    *(uint4*)dst = p.u4;
}

// ---------------------------------------------------------------------------
// Kernel A (r8 structure + scores epilogue): Wx = x @ W.T via f16 MFMA.
// Block = 64 m x 128 n, 256 thr = 4 waves, K chunked by 64, u16 staging.
// Epilogue 1: scores s_src/s_tgt from the f32 accumulators (each wave spans
// 2 heads; in-register dot with attn + shfl-reduce over ln) -> global.
// Epilogue 2: C -> LDS transpose -> coalesced f16 [bh][d][j] stores.
// ---------------------------------------------------------------------------
__global__ __launch_bounds__(256) void gemm_wxt(const unsigned short* __restrict__ xf,
                                                const unsigned short* __restrict__ wf,
                                                const float* __restrict__ attn,
                                                unsigned short* __restrict__ wxtg,
                                                float* __restrict__ s_src,
                                                float* __restrict__ s_tgt) {
    __shared__ __align__(16) unsigned short xs[64 * 64];    // [i][k] f16, row 128B
    __shared__ __align__(16) unsigned short pool[128 * 64]; // ws / tb alias, 16KB
    unsigned short* ws = pool;   // [n][k] f16, row 128B, swz (n&7)<<4
    unsigned short* tb = pool;   // [n][j] f16, row 128B, swz (n&7)<<4 (after GEMM)

    const int tid = threadIdx.x;
    const int bid = blockIdx.x;
    const int m0 = (bid >> 1) * 64;
    const int n0 = (bid & 1) * 128;
    const int w = tid >> 6, l = tid & 63;
    const int q = l >> 4, ln = l & 15;
    const int iw = (w & 1) * 32, nw = (w >> 1) * 64;

    f32x4 acc[2][4];
    #pragma unroll
    for (int g = 0; g < 2; ++g)
        #pragma unroll
        for (int t = 0; t < 4; ++t) acc[g][t] = (f32x4){0.f, 0.f, 0.f, 0.f};

    for (int kc = 0; kc < 256; kc += 64) {
        __syncthreads();
        // stage x tile 64x64 u16: 512 uint4, 2/thread
        #pragma unroll
        for (int p = 0; p < 2; ++p) {
            int idx = p * 256 + tid;
            int row = idx >> 3, c = idx & 7;
            uint4 v = *(const uint4*)(xf + (size_t)(m0 + row) * 256 + kc + c * 8);
            *(uint4*)((char*)xs + ((row * 128 + c * 16) ^ ((row & 7) << 4))) = v;
        }
        // stage W tile 128x64 u16: 1024 uint4, 4/thread
        #pragma unroll
        for (int p = 0; p < 4; ++p) {
            int idx = p * 256 + tid;
            int n = idx >> 3, c = idx & 7;
            uint4 v = *(const uint4*)(wf + (size_t)(n0 + n) * 256 + kc + c * 8);
            *(uint4*)((char*)ws + ((n * 128 + c * 16) ^ ((n & 7) << 4))) = v;
        }
        __syncthreads();

        #pragma unroll
        for (int ks = 0; ks < 2; ++ks) {
            const int kb = ks * 64 + q * 16;
            f16x8 af[2];
            #pragma unroll
            for (int g = 0; g < 2; ++g) {
                int row = iw + g * 16 + ln;
                uint4 raw = *(const uint4*)((const char*)xs +
                            ((row * 128 + kb) ^ ((row & 7) << 4)));
                PK8 pk; pk.u4 = raw;
                af[g] = pk.v;
            }
            #pragma unroll
            for (int t = 0; t < 4; ++t) {
                int n = nw + t * 16 + ln;
                uint4 raw = *(const uint4*)((const char*)ws +
                            ((n * 128 + kb) ^ ((n & 7) << 4)));
                PK8 pk; pk.u4 = raw;
                f16x8 bf = pk.v;
                acc[0][t] = __builtin_amdgcn_mfma_f32_16x16x32_f16(af[0], bf, acc[0][t], 0, 0, 0);
                acc[1][t] = __builtin_amdgcn_mfma_f32_16x16x32_f16(af[1], bf, acc[1][t], 0, 0, 0);
            }
        }
    }

    // ---- Epilogue 1: scores. Wave covers heads h0,h0+1; cols d = t*16+ln ----
    {
        const int h0 = (n0 + nw) >> 5;
        float avs[2][2], avt[2][2];
        #pragma unroll
        for (int hh = 0; hh < 2; ++hh)
            #pragma unroll
            for (int t = 0; t < 2; ++t) {
                avs[hh][t] = attn[(h0 + hh) * 64 + t * 16 + ln];
                avt[hh][t] = attn[(h0 + hh) * 64 + 32 + t * 16 + ln];
            }
        const int bb8 = (m0 >> 9) * 8;
        const int jbase = (m0 & 511) + iw;
        #pragma unroll
        for (int g = 0; g < 2; ++g)
            #pragma unroll
            for (int r = 0; r < 4; ++r) {
                float ps0 = acc[g][0][r] * avs[0][0] + acc[g][1][r] * avs[0][1];
                float pt0 = acc[g][0][r] * avt[0][0] + acc[g][1][r] * avt[0][1];
                float ps1 = acc[g][2][r] * avs[1][0] + acc[g][3][r] * avs[1][1];
                float pt1 = acc[g][2][r] * avt[1][0] + acc[g][3][r] * avt[1][1];
                #pragma unroll
                for (int off = 1; off < 16; off <<= 1) {
                    ps0 += __shfl_xor(ps0, off);
                    pt0 += __shfl_xor(pt0, off);
                    ps1 += __shfl_xor(ps1, off);
                    pt1 += __shfl_xor(pt1, off);
                }
                if (ln == 0) {
                    int j = jbase + g * 16 + q * 4 + r;
                    s_src[(bb8 + h0) * 512 + j] = ps0;
                    s_tgt[(bb8 + h0) * 512 + j] = pt0;
                    s_src[(bb8 + h0 + 1) * 512 + j] = ps1;
                    s_tgt[(bb8 + h0 + 1) * 512 + j] = pt1;
                }
            }
    }

    __syncthreads();   // done reading ws -> tb may overwrite
    // Epilogue 2: C frags -> transpose buffer tb[n][j_local] f16
    #pragma unroll
    for (int g = 0; g < 2; ++g)
        #pragma unroll
        for (int t = 0; t < 4; ++t)
            #pragma unroll
            for (int r = 0; r < 4; ++r) {
                int n  = nw + t * 16 + ln;            // C col
                int jl = iw + g * 16 + q * 4 + r;     // C row
                PK1 hv; hv.h = (_Float16)acc[g][t][r];
                *(unsigned short*)((char*)tb + ((n * 128 + jl * 2) ^ ((n & 7) << 4))) = hv.u;
            }
    __syncthreads();
    // coalesced readout: 1024 16B chunks, 4/thread
    {
        const int b = m0 >> 9, j0 = m0 & 511;
        #pragma unroll
        for (int p = 0; p < 4; ++p) {
            int idx = p * 256 + tid;
            int n = idx >> 3, c = idx & 7;
            uint4 v = *(const uint4*)((const char*)tb + ((n * 128 + c * 16) ^ ((n & 7) << 4)));
            int nn = n0 + n;                          // = h*32 + d
            *(uint4*)(wxtg + ((size_t)(b * 256 + nn) * 512 + j0 + c * 8)) = v;
        }
    }
}

// ---------------------------------------------------------------------------
// Kernel B (r8 structure minus scores phase): softmax + PV + ELU.
// Grid 512 = (half, b, h). 512 thr = 8 waves; wave owns 32 i-rows (g=2).
// Stage wxt 32KB + stf from global s_tgt; block max; PV with scalar P-gen.
// ---------------------------------------------------------------------------
__global__ __launch_bounds__(512, 4) void gat_attn(const unsigned short* __restrict__ wxtg,
                                                   const float* __restrict__ s_src,
                                                   const float* __restrict__ s_tgt,
                                                   float* __restrict__ out) {
    __shared__ __align__(16) unsigned short wxt[32 * 512];  // [d][j] f16, row 1KB, swz (d&7)<<4
    __shared__ float stf[512];    // s_tgt * LOG2E
    __shared__ float red_s[8];

    const int bid = blockIdx.x;
    const int bh = bid & 255, half = bid >> 8;
    const int b = bh >> 3, h = bh & 7;
    const int tid = threadIdx.x;
    const int w = tid >> 6, l = tid & 63;
    const int q = l >> 4, ln = l & 15;

    // ---- stage WxT slice: 32KB straight f16 copy ----
    {
        const unsigned short* src = wxtg + (size_t)bh * 32 * 512;
        const int d = tid >> 4, cs = tid & 15;
        #pragma unroll
        for (int p = 0; p < 4; ++p) {
            int c = p * 16 + cs;
            uint4 v = *(const uint4*)(src + d * 512 + c * 8);
            *(uint4*)((char*)wxt + ((d * 1024 + c * 16) ^ ((d & 7) << 4))) = v;
        }
    }
    // ---- stage stf + block max ----
    {
        float stv = s_tgt[bh * 512 + tid] * LOG2E;
        stf[tid] = stv;
        float m = stv;
        #pragma unroll
        for (int off = 32; off > 0; off >>= 1)
            m = fmaxf(m, __shfl_xor(m, off));
        if (l == 0) red_s[w] = m;
    }
    __syncthreads();
    float maxtK = red_s[0];
    #pragma unroll
    for (int ww = 1; ww < 8; ++ww) maxtK = fmaxf(maxtK, red_s[ww]);

    // ---- wave owns rows i = half*256 + w*32 + g*16 + ln ----
    const int ibase = half * 256 + w * 32;
    float ciK[2], miK[2];
    #pragma unroll
    for (int g = 0; g < 2; ++g) {
        float cc = s_src[bh * 512 + ibase + g * 16 + ln] * LOG2E;
        float cm = cc + maxtK;
        miK[g] = fmaxf(cm, NEG_SLOPE * cm);
        ciK[g] = cc;
    }

    f32x4 acc[2][2];
    #pragma unroll
    for (int g = 0; g < 2; ++g) {
        acc[g][0] = (f32x4){0.f, 0.f, 0.f, 0.f};
        acc[g][1] = (f32x4){0.f, 0.f, 0.f, 0.f};
    }
    float pd[2] = {0.f, 0.f};

    for (int kk = 0; kk < 16; ++kk) {
        const int j0 = kk * 32 + q * 8;
        float4 s0 = *(const float4*)(stf + j0);
        float4 s1 = *(const float4*)(stf + j0 + 4);
        float st[8] = {s0.x, s0.y, s0.z, s0.w, s1.x, s1.y, s1.z, s1.w};

        f16x8 bf[2];
        #pragma unroll
        for (int dt = 0; dt < 2; ++dt) {
            int d = dt * 16 + ln;
            int bb = d * 1024 + kk * 64 + q * 16;
            uint4 raw = *(const uint4*)((const char*)wxt + (bb ^ ((d & 7) << 4)));
            PK8 pk; pk.u4 = raw;
            bf[dt] = pk.v;
        }

        #pragma unroll
        for (int g = 0; g < 2; ++g) {
            f16x8 pa;
            float s = 0.f;
            #pragma unroll
            for (int e = 0; e < 8; ++e) {
                float eK = ciK[g] + st[e];
                float lr = fmaxf(eK, NEG_SLOPE * eK);
                float p = EXP2F(lr - miK[g]);
                s += p;
                pa[e] = (_Float16)p;
            }
            pd[g] += s;
            acc[g][0] = __builtin_amdgcn_mfma_f32_16x16x32_f16(pa, bf[0], acc[g][0], 0, 0, 0);
            acc[g][1] = __builtin_amdgcn_mfma_f32_16x16x32_f16(pa, bf[1], acc[g][1], 0, 0, 0);
        }
    }

    float inv[2];
    #pragma unroll
    for (int g = 0; g < 2; ++g) {
        float s = pd[g];
        s += __shfl_xor(s, 16);
        s += __shfl_xor(s, 32);
        inv[g] = 1.f / s;
    }
    #pragma unroll
    for (int g = 0; g < 2; ++g)
        #pragma unroll
        for (int dt = 0; dt < 2; ++dt)
            #pragma unroll
            for (int r = 0; r < 4; ++r) {
                int row = q * 4 + r;
                float dn = __shfl(inv[g], row);    // lane 'row' holds denom for i-local=row
                float o = acc[g][dt][r] * dn;
                o = o > 0.f ? o : (__expf(o) - 1.f);
                size_t i = (size_t)(b * 512 + half * 256 + w * 32 + g * 16 + row);
                out[i * 256 + h * 32 + dt * 16 + ln] = o;
            }
}

// ---------------------------------------------------------------------------
extern "C" void kernel_launch(void* const* d_in, const int* in_sizes, int n_in,
                              void* d_out, int out_size, void* d_ws, size_t ws_size,
                              hipStream_t stream) {
    const float* x    = (const float*)d_in[0];   // (32,512,256)
    const float* W    = (const float*)d_in[1];   // (256,256)
    const float* attn = (const float*)d_in[2];   // (1,8,64)
    float* out = (float*)d_out;                  // (32,512,256)

    unsigned short* xf   = (unsigned short*)d_ws;             // f16 x, 8.39 MB
    unsigned short* wf   = xf + (size_t)32 * 512 * 256;       // f16 W, 131 KB
    unsigned short* wxtg = wf + 256 * 256;                    // f16 [bh][d][j], 8.39 MB
    float* s_src = (float*)(wxtg + (size_t)256 * 32 * 512);   // [bh][j] f32, 524 KB
    float* s_tgt = s_src + 256 * 512;                         // [bh][j] f32, 524 KB

    cvt_f16<<<(XN_CHUNKS + WN_CHUNKS + 255) / 256, 256, 0, stream>>>(x, W, xf, wf);
    gemm_wxt<<<512, 256, 0, stream>>>(xf, wf, attn, wxtg, s_src, s_tgt);
    gat_attn<<<512, 512, 0, stream>>>(wxtg, s_src, s_tgt, out);
}